// Round 5
// baseline (305.366 us; speedup 1.0000x reference)
//
#include <hip/hip_runtime.h>
#include <hip/hip_bf16.h>

#define NNODES 50000
#define IN_DIM 256
#define OUT_DIM 128
#define SCALE 1.8f
#define ALPHA 0.15f
#define NB_SCAN 196  // ceil(50000/256)

typedef unsigned short ushort_t;
typedef __attribute__((ext_vector_type(8))) short bf16x8;
typedef __attribute__((ext_vector_type(4))) float f32x4;

// ---------------- helpers: bf16 pack/unpack ----------------

__device__ __forceinline__ unsigned short f2bf_rne(float f) {
    unsigned int u = __float_as_uint(f);
    unsigned int r = u + 0x7fffu + ((u >> 16) & 1u);  // round-to-nearest-even
    return (unsigned short)(r >> 16);
}

__device__ __forceinline__ float bf2f(unsigned short h) {
    return __uint_as_float((unsigned int)h << 16);
}

__device__ __forceinline__ float2 bf2_to_f2(unsigned int p) {
    float2 f;
    f.x = __uint_as_float(p << 16);
    f.y = __uint_as_float(p & 0xffff0000u);
    return f;
}

__device__ __forceinline__ unsigned int f2_to_bf2(float x, float y) {
    return (unsigned int)f2bf_rne(x) | ((unsigned int)f2bf_rne(y) << 16);
}

// ---------------- degree count ----------------

__global__ void zero_cnt_kernel(int* __restrict__ cnt) {
    int i = blockIdx.x * blockDim.x + threadIdx.x;
    if (i < NNODES) cnt[i] = 0;
}

__global__ void deg_scatter_kernel(const int* __restrict__ col, int* __restrict__ cnt, int E) {
    int e = blockIdx.x * blockDim.x + threadIdx.x;
    if (e < E) atomicAdd(&cnt[col[e]], 1);
}

// ---------------- W split-precision conversion: W -> Whi + Wlo (bf16) ----------------

__global__ void wcvt_kernel(const float* __restrict__ W,
                            ushort_t* __restrict__ Whi, ushort_t* __restrict__ Wlo) {
    int i = blockIdx.x * blockDim.x + threadIdx.x;
    if (i < OUT_DIM * IN_DIM) {
        float w = W[i];
        unsigned short h = f2bf_rne(w);
        unsigned short l = f2bf_rne(w - bf2f(h));
        Whi[i] = h;
        Wlo[i] = l;
    }
}

// ---------------- exclusive scan (3-pass) over cnt -> off, cur; fused dinv/selfw ----------------

__global__ void scan_pass1(const int* __restrict__ cnt, int* __restrict__ part) {
    __shared__ int sd[256];
    int t = threadIdx.x;
    int i = blockIdx.x * 256 + t;
    sd[t] = (i < NNODES) ? cnt[i] : 0;
    __syncthreads();
    for (int s = 128; s > 0; s >>= 1) {
        if (t < s) sd[t] += sd[t + s];
        __syncthreads();
    }
    if (t == 0) part[blockIdx.x] = sd[0];
}

__global__ void scan_pass2(int* __restrict__ part) {
    __shared__ int s[256];
    int t = threadIdx.x;
    int v = (t < NB_SCAN) ? part[t] : 0;
    s[t] = v;
    __syncthreads();
    for (int o = 1; o < 256; o <<= 1) {
        int u = (t >= o) ? s[t - o] : 0;
        __syncthreads();
        s[t] += u;
        __syncthreads();
    }
    if (t < NB_SCAN) part[t] = (t == 0) ? 0 : s[t - 1];
}

__global__ void scan_pass3(const int* __restrict__ cnt, const int* __restrict__ part,
                           int* __restrict__ off, int* __restrict__ cur,
                           float* __restrict__ dinv, float* __restrict__ selfw, int E) {
    __shared__ int s[256];
    int t = threadIdx.x;
    int i = blockIdx.x * 256 + t;
    int v = (i < NNODES) ? cnt[i] : 0;
    s[t] = v;
    __syncthreads();
    for (int o = 1; o < 256; o <<= 1) {
        int u = (t >= o) ? s[t - o] : 0;
        __syncthreads();
        s[t] += u;
        __syncthreads();
    }
    int excl = part[blockIdx.x] + ((t == 0) ? 0 : s[t - 1]);
    if (i < NNODES) {
        off[i] = excl;
        cur[i] = excl;
        float d = rsqrtf((float)(v + 1));
        dinv[i] = d;
        selfw[i] = (1.0f - ALPHA) * d * d;
    }
    if (i == NNODES - 1) off[NNODES] = E;
}

__global__ void csr_fill_kernel(const int* __restrict__ row, const int* __restrict__ col,
                                const float* __restrict__ dinv, int* __restrict__ cur,
                                int* __restrict__ csr_row, float* __restrict__ csr_w, int E) {
    int e = blockIdx.x * blockDim.x + threadIdx.x;
    if (e < E) {
        int c = col[e];
        int r = row[e];
        int p = atomicAdd(&cur[c], 1);
        csr_row[p] = r;
        csr_w[p] = (1.0f - ALPHA) * dinv[r] * dinv[c];
    }
}

// ---------------- MFMA GEMM + bias + L2-normalize (split-precision bf16) ----------------
// One block = 256 threads = 4 waves; wave w computes rows [blk*64 + w*16, +16) x all 128 cols.
// A-frag: x row, 8 contiguous k from LDS (converted fp32->bf16 hi/lo on stage-in).
// B-frag: W row (= B column), 8 contiguous k direct from global bf16 Whi/Wlo.
// acc = Ahi*Bhi + Alo*Bhi + Ahi*Blo (3 MFMAs) -> fp32-grade accuracy.
// C/D layout: col = lane&15, row = (lane>>4)*4 + reg  [m89-verified].
// A layout:  A[m = lane&15][k = (lane>>4)*8 + j]      [m120-verified].

#define XPAD 264  // 256 + 8 ushorts; row stride 528 B (16B-aligned, odd*16 -> 2-way banks)

__global__ void __launch_bounds__(256) gemm_norm_kernel(
        const float* __restrict__ x,
        const ushort_t* __restrict__ Whi, const ushort_t* __restrict__ Wlo,
        const float* __restrict__ b, float* __restrict__ hn,
        ushort_t* __restrict__ zb) {
    __shared__ __align__(16) ushort_t xhi[64][XPAD];
    __shared__ __align__(16) ushort_t xlo[64][XPAD];

    const int t = threadIdx.x;
    const int rowBase = blockIdx.x * 64;

    // ---- stage x (64 rows x 256 k), fp32 -> bf16 hi/lo ----
    #pragma unroll
    for (int it = 0; it < 16; ++it) {
        int s = it * 256 + t;       // 0..4095 float4 slots
        int r = s >> 6;             // row 0..63
        int ks = (s & 63) * 4;      // k 0..252
        int grow = rowBase + r;
        float4 v = make_float4(0.f, 0.f, 0.f, 0.f);
        if (grow < NNODES) v = *(const float4*)(x + (size_t)grow * IN_DIM + ks);
        unsigned short h0 = f2bf_rne(v.x), h1 = f2bf_rne(v.y),
                       h2 = f2bf_rne(v.z), h3 = f2bf_rne(v.w);
        unsigned short l0 = f2bf_rne(v.x - bf2f(h0)), l1 = f2bf_rne(v.y - bf2f(h1)),
                       l2 = f2bf_rne(v.z - bf2f(h2)), l3 = f2bf_rne(v.w - bf2f(h3));
        uint2 ph, pl;
        ph.x = (unsigned int)h0 | ((unsigned int)h1 << 16);
        ph.y = (unsigned int)h2 | ((unsigned int)h3 << 16);
        pl.x = (unsigned int)l0 | ((unsigned int)l1 << 16);
        pl.y = (unsigned int)l2 | ((unsigned int)l3 << 16);
        *(uint2*)&xhi[r][ks] = ph;
        *(uint2*)&xlo[r][ks] = pl;
    }
    __syncthreads();

    // ---- MFMA main loop ----
    const int wv = t >> 6;
    const int lane = t & 63;
    const int q = lane >> 4;     // quad 0..3
    const int c = lane & 15;     // col-in-tile / row-in-tile selector
    const int m0 = wv * 16;

    f32x4 acc[8];
    #pragma unroll
    for (int nt = 0; nt < 8; ++nt) {
        float bv = b[nt * 16 + c];
        acc[nt][0] = bv; acc[nt][1] = bv; acc[nt][2] = bv; acc[nt][3] = bv;
    }

    #pragma unroll
    for (int kt = 0; kt < 8; ++kt) {
        const int kb = kt * 32 + q * 8;
        bf16x8 ahi = *(const bf16x8*)&xhi[m0 + c][kb];
        bf16x8 alo = *(const bf16x8*)&xlo[m0 + c][kb];
        #pragma unroll
        for (int nt = 0; nt < 8; ++nt) {
            const size_t woff = (size_t)(nt * 16 + c) * IN_DIM + kb;
            bf16x8 bhi = *(const bf16x8*)(Whi + woff);
            bf16x8 blo = *(const bf16x8*)(Wlo + woff);
            acc[nt] = __builtin_amdgcn_mfma_f32_16x16x32_bf16(ahi, bhi, acc[nt], 0, 0, 0);
            acc[nt] = __builtin_amdgcn_mfma_f32_16x16x32_bf16(alo, bhi, acc[nt], 0, 0, 0);
            acc[nt] = __builtin_amdgcn_mfma_f32_16x16x32_bf16(ahi, blo, acc[nt], 0, 0, 0);
        }
    }

    // ---- row L2-norm via shuffle butterfly over the 16 low lanes ----
    float psum[4];
    #pragma unroll
    for (int r = 0; r < 4; ++r) {
        float s = 0.f;
        #pragma unroll
        for (int nt = 0; nt < 8; ++nt) s += acc[nt][r] * acc[nt][r];
        psum[r] = s;
    }
    #pragma unroll
    for (int mask = 1; mask < 16; mask <<= 1) {
        #pragma unroll
        for (int r = 0; r < 4; ++r) psum[r] += __shfl_xor(psum[r], mask);
    }
    float scl[4];
    #pragma unroll
    for (int r = 0; r < 4; ++r) scl[r] = SCALE / fmaxf(sqrtf(psum[r]), 1e-12f);

    // ---- store hn (fp32) + zb (bf16) ----
    #pragma unroll
    for (int r = 0; r < 4; ++r) {
        int grow = rowBase + m0 + q * 4 + r;
        if (grow < NNODES) {
            #pragma unroll
            for (int nt = 0; nt < 8; ++nt) {
                float o = acc[nt][r] * scl[r];
                size_t idx = (size_t)grow * OUT_DIM + nt * 16 + c;
                hn[idx] = o;
                zb[idx] = f2bf_rne(o);
            }
        }
    }
}

// ---------------- gather propagation: wave-per-node, bf16 state ----------------

template <int FINAL>
__global__ void __launch_bounds__(256) gather_kernel(
        const int* __restrict__ off, const int* __restrict__ csr_row,
        const float* __restrict__ csr_w, const float* __restrict__ selfw,
        const unsigned int* __restrict__ zb, const float* __restrict__ hn,
        unsigned int* __restrict__ zout_b, float* __restrict__ zout_f) {
    const int wv = threadIdx.x >> 6;
    const int lane = threadIdx.x & 63;
    const int c = blockIdx.x * 4 + wv;  // grid*4 == NNODES exactly
    const int s = off[c];
    const int e = off[c + 1];

    float2 acc;
    {
        float sw = selfw[c];
        float2 zc = bf2_to_f2(zb[(size_t)c * 64 + lane]);
        acc.x = sw * zc.x;
        acc.y = sw * zc.y;
    }

    for (int base = s; base < e; base += 64) {
        int n = e - base;
        if (n > 64) n = 64;
        int idx = 0;
        float w = 0.f;
        if (lane < n) {
            idx = csr_row[base + lane];
            w = csr_w[base + lane];
        }
        int j = 0;
        for (; j + 4 <= n; j += 4) {
            int r0 = __shfl(idx, j + 0), r1 = __shfl(idx, j + 1);
            int r2 = __shfl(idx, j + 2), r3 = __shfl(idx, j + 3);
            float w0 = __shfl(w, j + 0), w1 = __shfl(w, j + 1);
            float w2 = __shfl(w, j + 2), w3 = __shfl(w, j + 3);
            unsigned int p0 = zb[(size_t)r0 * 64 + lane];
            unsigned int p1 = zb[(size_t)r1 * 64 + lane];
            unsigned int p2 = zb[(size_t)r2 * 64 + lane];
            unsigned int p3 = zb[(size_t)r3 * 64 + lane];
            float2 v0 = bf2_to_f2(p0), v1 = bf2_to_f2(p1);
            float2 v2 = bf2_to_f2(p2), v3 = bf2_to_f2(p3);
            acc.x += w0 * v0.x; acc.y += w0 * v0.y;
            acc.x += w1 * v1.x; acc.y += w1 * v1.y;
            acc.x += w2 * v2.x; acc.y += w2 * v2.y;
            acc.x += w3 * v3.x; acc.y += w3 * v3.y;
        }
        for (; j < n; ++j) {
            int r = __shfl(idx, j);
            float ww = __shfl(w, j);
            float2 v = bf2_to_f2(zb[(size_t)r * 64 + lane]);
            acc.x += ww * v.x;
            acc.y += ww * v.y;
        }
    }

    float2 h = ((const float2*)hn)[(size_t)c * 64 + lane];
    float ox = acc.x + ALPHA * h.x;
    float oy = acc.y + ALPHA * h.y;
    if (FINAL) {
        ((float2*)zout_f)[(size_t)c * 64 + lane] = make_float2(ox, oy);
    } else {
        zout_b[(size_t)c * 64 + lane] = f2_to_bf2(ox, oy);
    }
}

extern "C" void kernel_launch(void* const* d_in, const int* in_sizes, int n_in,
                              void* d_out, int out_size, void* d_ws, size_t ws_size,
                              hipStream_t stream) {
    const float* x  = (const float*)d_in[0];
    const int*   ei = (const int*)d_in[1];
    const float* W  = (const float*)d_in[2];
    const float* b  = (const float*)d_in[3];
    float* out = (float*)d_out;

    int E = in_sizes[1] / 2;
    const int* row = ei;       // sources
    const int* col = ei + E;   // targets

    // workspace layout
    float* dinv  = (float*)d_ws;                        // 50048
    float* selfw = dinv + 50048;                        // 50048
    float* hn    = selfw + 50048;                       // 6,400,000 fp32
    unsigned int* zb  = (unsigned int*)(hn + (size_t)NNODES * OUT_DIM);  // 3.2M u32 (bf16x2)
    unsigned int* z1b = zb + (size_t)NNODES * 64;                        // 3.2M u32
    int*   cnt   = (int*)(z1b + (size_t)NNODES * 64);   // 50048
    int*   off   = cnt + 50048;                         // 50112 (N+1 used)
    int*   cur   = off + 50112;                         // 50048
    int*   part  = cur + 50048;                         // 256
    int*   csr_row = part + 256;                        // E
    float* csr_w   = (float*)(csr_row + ((E + 63) & ~63));  // E
    ushort_t* Whi = (ushort_t*)(csr_w + ((E + 63) & ~63));  // 32768
    ushort_t* Wlo = Whi + OUT_DIM * IN_DIM;                 // 32768

    zero_cnt_kernel<<<(NNODES + 255) / 256, 256, 0, stream>>>(cnt);
    deg_scatter_kernel<<<(E + 255) / 256, 256, 0, stream>>>(col, cnt, E);
    wcvt_kernel<<<(OUT_DIM * IN_DIM + 255) / 256, 256, 0, stream>>>(W, Whi, Wlo);

    scan_pass1<<<NB_SCAN, 256, 0, stream>>>(cnt, part);
    scan_pass2<<<1, 256, 0, stream>>>(part);
    scan_pass3<<<NB_SCAN, 256, 0, stream>>>(cnt, part, off, cur, dinv, selfw, E);
    csr_fill_kernel<<<(E + 255) / 256, 256, 0, stream>>>(row, col, dinv, cur, csr_row, csr_w, E);

    gemm_norm_kernel<<<(NNODES + 63) / 64, 256, 0, stream>>>(x, Whi, Wlo, b, hn, (ushort_t*)zb);

    gather_kernel<0><<<NNODES / 4, 256, 0, stream>>>(off, csr_row, csr_w, selfw, zb, hn, z1b, nullptr);
    gather_kernel<1><<<NNODES / 4, 256, 0, stream>>>(off, csr_row, csr_w, selfw, z1b, hn, nullptr, out);
}

// Round 6
// 301.255 us; speedup vs baseline: 1.0136x; 1.0136x over previous
//
#include <hip/hip_runtime.h>
#include <hip/hip_bf16.h>

#define NNODES 50000
#define IN_DIM 256
#define OUT_DIM 128
#define SCALE 1.8f
#define ALPHA 0.15f
#define NB_SCAN 196  // ceil(50000/256)

typedef unsigned short ushort_t;
typedef __attribute__((ext_vector_type(8))) short bf16x8;
typedef __attribute__((ext_vector_type(4))) float f32x4;

// ---------------- helpers: bf16 pack/unpack ----------------

__device__ __forceinline__ unsigned short f2bf_rne(float f) {
    unsigned int u = __float_as_uint(f);
    unsigned int r = u + 0x7fffu + ((u >> 16) & 1u);  // round-to-nearest-even
    return (unsigned short)(r >> 16);
}

__device__ __forceinline__ float bf2f(unsigned short h) {
    return __uint_as_float((unsigned int)h << 16);
}

__device__ __forceinline__ float2 bf2_to_f2(unsigned int p) {
    float2 f;
    f.x = __uint_as_float(p << 16);
    f.y = __uint_as_float(p & 0xffff0000u);
    return f;
}

__device__ __forceinline__ unsigned int f2_to_bf2(float x, float y) {
    return (unsigned int)f2bf_rne(x) | ((unsigned int)f2bf_rne(y) << 16);
}

// ---------------- degree count ----------------

__global__ void zero_cnt_kernel(int* __restrict__ cnt) {
    int i = blockIdx.x * blockDim.x + threadIdx.x;
    if (i < NNODES) cnt[i] = 0;
}

__global__ void deg_scatter_kernel(const int* __restrict__ col, int* __restrict__ cnt, int E) {
    int e = blockIdx.x * blockDim.x + threadIdx.x;
    if (e < E) atomicAdd(&cnt[col[e]], 1);
}

// ---------------- W split-precision conversion: W -> Whi + Wlo (bf16) ----------------

__global__ void wcvt_kernel(const float* __restrict__ W,
                            ushort_t* __restrict__ Whi, ushort_t* __restrict__ Wlo) {
    int i = blockIdx.x * blockDim.x + threadIdx.x;
    if (i < OUT_DIM * IN_DIM) {
        float w = W[i];
        unsigned short h = f2bf_rne(w);
        unsigned short l = f2bf_rne(w - bf2f(h));
        Whi[i] = h;
        Wlo[i] = l;
    }
}

// ---------------- exclusive scan (3-pass) over cnt -> off, cur; fused dinv/selfw ----------------

__global__ void scan_pass1(const int* __restrict__ cnt, int* __restrict__ part) {
    __shared__ int sd[256];
    int t = threadIdx.x;
    int i = blockIdx.x * 256 + t;
    sd[t] = (i < NNODES) ? cnt[i] : 0;
    __syncthreads();
    for (int s = 128; s > 0; s >>= 1) {
        if (t < s) sd[t] += sd[t + s];
        __syncthreads();
    }
    if (t == 0) part[blockIdx.x] = sd[0];
}

__global__ void scan_pass2(int* __restrict__ part) {
    __shared__ int s[256];
    int t = threadIdx.x;
    int v = (t < NB_SCAN) ? part[t] : 0;
    s[t] = v;
    __syncthreads();
    for (int o = 1; o < 256; o <<= 1) {
        int u = (t >= o) ? s[t - o] : 0;
        __syncthreads();
        s[t] += u;
        __syncthreads();
    }
    if (t < NB_SCAN) part[t] = (t == 0) ? 0 : s[t - 1];
}

__global__ void scan_pass3(const int* __restrict__ cnt, const int* __restrict__ part,
                           int* __restrict__ off, int* __restrict__ cur,
                           float* __restrict__ dinv, float* __restrict__ selfw, int E) {
    __shared__ int s[256];
    int t = threadIdx.x;
    int i = blockIdx.x * 256 + t;
    int v = (i < NNODES) ? cnt[i] : 0;
    s[t] = v;
    __syncthreads();
    for (int o = 1; o < 256; o <<= 1) {
        int u = (t >= o) ? s[t - o] : 0;
        __syncthreads();
        s[t] += u;
        __syncthreads();
    }
    int excl = part[blockIdx.x] + ((t == 0) ? 0 : s[t - 1]);
    if (i < NNODES) {
        off[i] = excl;
        cur[i] = excl;
        float d = rsqrtf((float)(v + 1));
        dinv[i] = d;
        selfw[i] = (1.0f - ALPHA) * d * d;
    }
    if (i == NNODES - 1) off[NNODES] = E;
}

__global__ void csr_fill_kernel(const int* __restrict__ row, const int* __restrict__ col,
                                const float* __restrict__ dinv, int* __restrict__ cur,
                                int* __restrict__ csr_row, float* __restrict__ csr_w, int E) {
    int e = blockIdx.x * blockDim.x + threadIdx.x;
    if (e < E) {
        int c = col[e];
        int r = row[e];
        int p = atomicAdd(&cur[c], 1);
        csr_row[p] = r;
        csr_w[p] = (1.0f - ALPHA) * dinv[r] * dinv[c];
    }
}

// ---------------- MFMA GEMM + bias + L2-normalize (split-precision bf16) ----------------
// One block = 256 threads = 4 waves; wave w computes rows [blk*64 + w*16, +16) x all 128 cols.
// A-frag: x row, 8 contiguous k from LDS (converted fp32->bf16 hi/lo on stage-in).
// B-frag: W row (= B column), 8 contiguous k from global bf16 Whi/Wlo,
//         REGISTER DOUBLE-BUFFERED across kt: all 16 loads for kt+1 issued as one
//         batch before the 24-MFMA burst for kt (fix for R5's serialized B loads).
// acc = Ahi*Bhi + Alo*Bhi + Ahi*Blo (3 MFMAs) -> fp32-grade accuracy.
// C/D layout: col = lane&15, row = (lane>>4)*4 + reg  [m89-verified].
// A layout:  A[m = lane&15][k = (lane>>4)*8 + j]      [m120-verified].

#define XPAD 264  // 256 + 8 ushorts; row stride 528 B (16B-aligned)

__global__ void __launch_bounds__(256, 2) gemm_norm_kernel(
        const float* __restrict__ x,
        const ushort_t* __restrict__ Whi, const ushort_t* __restrict__ Wlo,
        const float* __restrict__ b, float* __restrict__ hn,
        ushort_t* __restrict__ zb) {
    __shared__ __align__(16) ushort_t xhi[64][XPAD];
    __shared__ __align__(16) ushort_t xlo[64][XPAD];

    const int t = threadIdx.x;
    const int rowBase = blockIdx.x * 64;

    // ---- stage x (64 rows x 256 k), fp32 -> bf16 hi/lo ----
    #pragma unroll
    for (int it = 0; it < 16; ++it) {
        int s = it * 256 + t;       // 0..4095 float4 slots
        int r = s >> 6;             // row 0..63
        int ks = (s & 63) * 4;      // k 0..252
        int grow = rowBase + r;
        float4 v = make_float4(0.f, 0.f, 0.f, 0.f);
        if (grow < NNODES) v = *(const float4*)(x + (size_t)grow * IN_DIM + ks);
        unsigned short h0 = f2bf_rne(v.x), h1 = f2bf_rne(v.y),
                       h2 = f2bf_rne(v.z), h3 = f2bf_rne(v.w);
        unsigned short l0 = f2bf_rne(v.x - bf2f(h0)), l1 = f2bf_rne(v.y - bf2f(h1)),
                       l2 = f2bf_rne(v.z - bf2f(h2)), l3 = f2bf_rne(v.w - bf2f(h3));
        uint2 ph, pl;
        ph.x = (unsigned int)h0 | ((unsigned int)h1 << 16);
        ph.y = (unsigned int)h2 | ((unsigned int)h3 << 16);
        pl.x = (unsigned int)l0 | ((unsigned int)l1 << 16);
        pl.y = (unsigned int)l2 | ((unsigned int)l3 << 16);
        *(uint2*)&xhi[r][ks] = ph;
        *(uint2*)&xlo[r][ks] = pl;
    }
    __syncthreads();

    // ---- MFMA main loop ----
    const int wv = t >> 6;
    const int lane = t & 63;
    const int q = lane >> 4;     // quad 0..3
    const int c = lane & 15;     // col-in-tile / row-in-tile selector
    const int m0 = wv * 16;

    f32x4 acc[8];
    #pragma unroll
    for (int nt = 0; nt < 8; ++nt) {
        float bv = b[nt * 16 + c];
        acc[nt][0] = bv; acc[nt][1] = bv; acc[nt][2] = bv; acc[nt][3] = bv;
    }

    // per-lane W base: row (nt*16 + c), k offset q*8
    const size_t wbase = (size_t)c * IN_DIM + q * 8;

    bf16x8 bhi[2][8], blo[2][8];
    #pragma unroll
    for (int nt = 0; nt < 8; ++nt) {
        size_t woff = wbase + (size_t)nt * 16 * IN_DIM;  // kt = 0
        bhi[0][nt] = *(const bf16x8*)(Whi + woff);
        blo[0][nt] = *(const bf16x8*)(Wlo + woff);
    }

    #pragma unroll
    for (int kt = 0; kt < 8; ++kt) {
        const int cur = kt & 1;
        const int nxt = cur ^ 1;
        const int kb = kt * 32 + q * 8;
        bf16x8 ahi = *(const bf16x8*)&xhi[m0 + c][kb];
        bf16x8 alo = *(const bf16x8*)&xlo[m0 + c][kb];

        if (kt < 7) {
            #pragma unroll
            for (int nt = 0; nt < 8; ++nt) {
                size_t woff = wbase + (size_t)nt * 16 * IN_DIM + (kt + 1) * 32;
                bhi[nxt][nt] = *(const bf16x8*)(Whi + woff);
                blo[nxt][nt] = *(const bf16x8*)(Wlo + woff);
            }
        }

        #pragma unroll
        for (int nt = 0; nt < 8; ++nt) {
            acc[nt] = __builtin_amdgcn_mfma_f32_16x16x32_bf16(ahi, bhi[cur][nt], acc[nt], 0, 0, 0);
            acc[nt] = __builtin_amdgcn_mfma_f32_16x16x32_bf16(alo, bhi[cur][nt], acc[nt], 0, 0, 0);
            acc[nt] = __builtin_amdgcn_mfma_f32_16x16x32_bf16(ahi, blo[cur][nt], acc[nt], 0, 0, 0);
        }
    }

    // ---- row L2-norm via shuffle butterfly over the 16 low lanes ----
    float psum[4];
    #pragma unroll
    for (int r = 0; r < 4; ++r) {
        float s = 0.f;
        #pragma unroll
        for (int nt = 0; nt < 8; ++nt) s += acc[nt][r] * acc[nt][r];
        psum[r] = s;
    }
    #pragma unroll
    for (int mask = 1; mask < 16; mask <<= 1) {
        #pragma unroll
        for (int r = 0; r < 4; ++r) psum[r] += __shfl_xor(psum[r], mask);
    }
    float scl[4];
    #pragma unroll
    for (int r = 0; r < 4; ++r) scl[r] = SCALE / fmaxf(sqrtf(psum[r]), 1e-12f);

    // ---- store hn (fp32) + zb (bf16) ----
    #pragma unroll
    for (int r = 0; r < 4; ++r) {
        int grow = rowBase + m0 + q * 4 + r;
        if (grow < NNODES) {
            #pragma unroll
            for (int nt = 0; nt < 8; ++nt) {
                float o = acc[nt][r] * scl[r];
                size_t idx = (size_t)grow * OUT_DIM + nt * 16 + c;
                hn[idx] = o;
                zb[idx] = f2bf_rne(o);
            }
        }
    }
}

// ---------------- gather propagation: wave-per-node, bf16 state ----------------

template <int FINAL>
__global__ void __launch_bounds__(256) gather_kernel(
        const int* __restrict__ off, const int* __restrict__ csr_row,
        const float* __restrict__ csr_w, const float* __restrict__ selfw,
        const unsigned int* __restrict__ zb, const float* __restrict__ hn,
        unsigned int* __restrict__ zout_b, float* __restrict__ zout_f) {
    const int wv = threadIdx.x >> 6;
    const int lane = threadIdx.x & 63;
    const int c = blockIdx.x * 4 + wv;  // grid*4 == NNODES exactly
    const int s = off[c];
    const int e = off[c + 1];

    float2 acc;
    {
        float sw = selfw[c];
        float2 zc = bf2_to_f2(zb[(size_t)c * 64 + lane]);
        acc.x = sw * zc.x;
        acc.y = sw * zc.y;
    }

    for (int base = s; base < e; base += 64) {
        int n = e - base;
        if (n > 64) n = 64;
        int idx = 0;
        float w = 0.f;
        if (lane < n) {
            idx = csr_row[base + lane];
            w = csr_w[base + lane];
        }
        int j = 0;
        for (; j + 4 <= n; j += 4) {
            int r0 = __shfl(idx, j + 0), r1 = __shfl(idx, j + 1);
            int r2 = __shfl(idx, j + 2), r3 = __shfl(idx, j + 3);
            float w0 = __shfl(w, j + 0), w1 = __shfl(w, j + 1);
            float w2 = __shfl(w, j + 2), w3 = __shfl(w, j + 3);
            unsigned int p0 = zb[(size_t)r0 * 64 + lane];
            unsigned int p1 = zb[(size_t)r1 * 64 + lane];
            unsigned int p2 = zb[(size_t)r2 * 64 + lane];
            unsigned int p3 = zb[(size_t)r3 * 64 + lane];
            float2 v0 = bf2_to_f2(p0), v1 = bf2_to_f2(p1);
            float2 v2 = bf2_to_f2(p2), v3 = bf2_to_f2(p3);
            acc.x += w0 * v0.x; acc.y += w0 * v0.y;
            acc.x += w1 * v1.x; acc.y += w1 * v1.y;
            acc.x += w2 * v2.x; acc.y += w2 * v2.y;
            acc.x += w3 * v3.x; acc.y += w3 * v3.y;
        }
        for (; j < n; ++j) {
            int r = __shfl(idx, j);
            float ww = __shfl(w, j);
            float2 v = bf2_to_f2(zb[(size_t)r * 64 + lane]);
            acc.x += ww * v.x;
            acc.y += ww * v.y;
        }
    }

    float2 h = ((const float2*)hn)[(size_t)c * 64 + lane];
    float ox = acc.x + ALPHA * h.x;
    float oy = acc.y + ALPHA * h.y;
    if (FINAL) {
        ((float2*)zout_f)[(size_t)c * 64 + lane] = make_float2(ox, oy);
    } else {
        zout_b[(size_t)c * 64 + lane] = f2_to_bf2(ox, oy);
    }
}

extern "C" void kernel_launch(void* const* d_in, const int* in_sizes, int n_in,
                              void* d_out, int out_size, void* d_ws, size_t ws_size,
                              hipStream_t stream) {
    const float* x  = (const float*)d_in[0];
    const int*   ei = (const int*)d_in[1];
    const float* W  = (const float*)d_in[2];
    const float* b  = (const float*)d_in[3];
    float* out = (float*)d_out;

    int E = in_sizes[1] / 2;
    const int* row = ei;       // sources
    const int* col = ei + E;   // targets

    // workspace layout
    float* dinv  = (float*)d_ws;                        // 50048
    float* selfw = dinv + 50048;                        // 50048
    float* hn    = selfw + 50048;                       // 6,400,000 fp32
    unsigned int* zb  = (unsigned int*)(hn + (size_t)NNODES * OUT_DIM);  // 3.2M u32 (bf16x2)
    unsigned int* z1b = zb + (size_t)NNODES * 64;                        // 3.2M u32
    int*   cnt   = (int*)(z1b + (size_t)NNODES * 64);   // 50048
    int*   off   = cnt + 50048;                         // 50112 (N+1 used)
    int*   cur   = off + 50112;                         // 50048
    int*   part  = cur + 50048;                         // 256
    int*   csr_row = part + 256;                        // E
    float* csr_w   = (float*)(csr_row + ((E + 63) & ~63));  // E
    ushort_t* Whi = (ushort_t*)(csr_w + ((E + 63) & ~63));  // 32768
    ushort_t* Wlo = Whi + OUT_DIM * IN_DIM;                 // 32768

    zero_cnt_kernel<<<(NNODES + 255) / 256, 256, 0, stream>>>(cnt);
    deg_scatter_kernel<<<(E + 255) / 256, 256, 0, stream>>>(col, cnt, E);
    wcvt_kernel<<<(OUT_DIM * IN_DIM + 255) / 256, 256, 0, stream>>>(W, Whi, Wlo);

    scan_pass1<<<NB_SCAN, 256, 0, stream>>>(cnt, part);
    scan_pass2<<<1, 256, 0, stream>>>(part);
    scan_pass3<<<NB_SCAN, 256, 0, stream>>>(cnt, part, off, cur, dinv, selfw, E);
    csr_fill_kernel<<<(E + 255) / 256, 256, 0, stream>>>(row, col, dinv, cur, csr_row, csr_w, E);

    gemm_norm_kernel<<<(NNODES + 63) / 64, 256, 0, stream>>>(x, Whi, Wlo, b, hn, (ushort_t*)zb);

    gather_kernel<0><<<NNODES / 4, 256, 0, stream>>>(off, csr_row, csr_w, selfw, zb, hn, z1b, nullptr);
    gather_kernel<1><<<NNODES / 4, 256, 0, stream>>>(off, csr_row, csr_w, selfw, z1b, hn, nullptr, out);
}

// Round 7
// 262.722 us; speedup vs baseline: 1.1623x; 1.1467x over previous
//
#include <hip/hip_runtime.h>
#include <hip/hip_bf16.h>

#define NNODES 50000
#define IN_DIM 256
#define OUT_DIM 128
#define SCALE 1.8f
#define ALPHA 0.15f
#define NB_SCAN 196  // ceil(50000/256)

typedef unsigned short ushort_t;
typedef __attribute__((ext_vector_type(8))) short bf16x8;
typedef __attribute__((ext_vector_type(4))) float f32x4;

// ---------------- helpers: bf16 pack/unpack ----------------

__device__ __forceinline__ unsigned short f2bf_rne(float f) {
    unsigned int u = __float_as_uint(f);
    unsigned int r = u + 0x7fffu + ((u >> 16) & 1u);  // round-to-nearest-even
    return (unsigned short)(r >> 16);
}

__device__ __forceinline__ float bf2f(unsigned short h) {
    return __uint_as_float((unsigned int)h << 16);
}

__device__ __forceinline__ float2 bf2_to_f2(unsigned int p) {
    float2 f;
    f.x = __uint_as_float(p << 16);
    f.y = __uint_as_float(p & 0xffff0000u);
    return f;
}

__device__ __forceinline__ unsigned int f2_to_bf2(float x, float y) {
    return (unsigned int)f2bf_rne(x) | ((unsigned int)f2bf_rne(y) << 16);
}

// ---------------- degree count ----------------

__global__ void zero_cnt_kernel(int* __restrict__ cnt) {
    int i = blockIdx.x * blockDim.x + threadIdx.x;
    if (i < NNODES) cnt[i] = 0;
}

__global__ void deg_scatter_kernel(const int* __restrict__ col, int* __restrict__ cnt, int E) {
    int e = blockIdx.x * blockDim.x + threadIdx.x;
    if (e < E) atomicAdd(&cnt[col[e]], 1);
}

// ---------------- W split-precision conversion: W -> Whi + Wlo (bf16) ----------------

__global__ void wcvt_kernel(const float* __restrict__ W,
                            ushort_t* __restrict__ Whi, ushort_t* __restrict__ Wlo) {
    int i = blockIdx.x * blockDim.x + threadIdx.x;
    if (i < OUT_DIM * IN_DIM) {
        float w = W[i];
        unsigned short h = f2bf_rne(w);
        unsigned short l = f2bf_rne(w - bf2f(h));
        Whi[i] = h;
        Wlo[i] = l;
    }
}

// ---------------- exclusive scan (3-pass) over cnt -> off, cur; fused dinv/selfw ----------------

__global__ void scan_pass1(const int* __restrict__ cnt, int* __restrict__ part) {
    __shared__ int sd[256];
    int t = threadIdx.x;
    int i = blockIdx.x * 256 + t;
    sd[t] = (i < NNODES) ? cnt[i] : 0;
    __syncthreads();
    for (int s = 128; s > 0; s >>= 1) {
        if (t < s) sd[t] += sd[t + s];
        __syncthreads();
    }
    if (t == 0) part[blockIdx.x] = sd[0];
}

__global__ void scan_pass2(int* __restrict__ part) {
    __shared__ int s[256];
    int t = threadIdx.x;
    int v = (t < NB_SCAN) ? part[t] : 0;
    s[t] = v;
    __syncthreads();
    for (int o = 1; o < 256; o <<= 1) {
        int u = (t >= o) ? s[t - o] : 0;
        __syncthreads();
        s[t] += u;
        __syncthreads();
    }
    if (t < NB_SCAN) part[t] = (t == 0) ? 0 : s[t - 1];
}

__global__ void scan_pass3(const int* __restrict__ cnt, const int* __restrict__ part,
                           int* __restrict__ off, int* __restrict__ cur,
                           float* __restrict__ dinv, float* __restrict__ selfw, int E) {
    __shared__ int s[256];
    int t = threadIdx.x;
    int i = blockIdx.x * 256 + t;
    int v = (i < NNODES) ? cnt[i] : 0;
    s[t] = v;
    __syncthreads();
    for (int o = 1; o < 256; o <<= 1) {
        int u = (t >= o) ? s[t - o] : 0;
        __syncthreads();
        s[t] += u;
        __syncthreads();
    }
    int excl = part[blockIdx.x] + ((t == 0) ? 0 : s[t - 1]);
    if (i < NNODES) {
        off[i] = excl;
        cur[i] = excl;
        float d = rsqrtf((float)(v + 1));
        dinv[i] = d;
        selfw[i] = (1.0f - ALPHA) * d * d;
    }
    if (i == NNODES - 1) off[NNODES] = E;
}

__global__ void csr_fill_kernel(const int* __restrict__ row, const int* __restrict__ col,
                                const float* __restrict__ dinv, int* __restrict__ cur,
                                int* __restrict__ csr_row, float* __restrict__ csr_w, int E) {
    int e = blockIdx.x * blockDim.x + threadIdx.x;
    if (e < E) {
        int c = col[e];
        int r = row[e];
        int p = atomicAdd(&cur[c], 1);
        csr_row[p] = r;
        csr_w[p] = (1.0f - ALPHA) * dinv[r] * dinv[c];
    }
}

// ---------------- MFMA GEMM + bias + L2-normalize (split-precision bf16) ----------------
// Block = 256 thr = 4 waves, tile 64 rows x 128 cols. Wave wv computes ALL 64 rows x
// 32 cols [(2wv)*16 .. (2wv+2)*16): 4 m-tiles x 2 n-tiles.
// KEY (R6 fix): the wave's entire W working set is 2n x 8kt x hi/lo = 32 frags =
// 128 VGPRs, loaded ONCE before the staging barrier -> no global loads in the MFMA
// loop (R5/R6 showed the compiler sinks per-kt B loads next to MFMAs -> 4% MfmaUtil).
// acc = Ahi*Bhi + Alo*Bhi + Ahi*Blo (3 MFMAs) -> fp32-grade accuracy.
// C/D layout: col = lane&15, row = (lane>>4)*4 + reg  [m89-verified].
// A layout:  A[m = lane&15][k = (lane>>4)*8 + j]      [m120-verified].

#define XPAD 264  // 256 + 8 ushorts; row stride 528 B (16B-aligned)

__global__ void __launch_bounds__(256, 2) gemm_norm_kernel(
        const float* __restrict__ x,
        const ushort_t* __restrict__ Whi, const ushort_t* __restrict__ Wlo,
        const float* __restrict__ b, float* __restrict__ hn,
        ushort_t* __restrict__ zb) {
    __shared__ __align__(16) ushort_t xhi[64][XPAD];
    __shared__ __align__(16) ushort_t xlo[64][XPAD];

    const int t = threadIdx.x;
    const int wv = t >> 6;
    const int lane = t & 63;
    const int q = lane >> 4;     // quad 0..3
    const int c = lane & 15;
    const int rowBase = blockIdx.x * 64;

    // ---- W fragment preload (loop-invariant; issued BEFORE staging so latency
    //      is buried under the staging loop + barrier) ----
    bf16x8 wh[2][8], wl[2][8];
    float bias[2];
    #pragma unroll
    for (int j = 0; j < 2; ++j) {
        const size_t base = (size_t)((2 * wv + j) * 16 + c) * IN_DIM + q * 8;
        #pragma unroll
        for (int kt = 0; kt < 8; ++kt) {
            wh[j][kt] = *(const bf16x8*)(Whi + base + kt * 32);
            wl[j][kt] = *(const bf16x8*)(Wlo + base + kt * 32);
        }
        bias[j] = b[(2 * wv + j) * 16 + c];
    }

    // ---- stage x (64 rows x 256 k), fp32 -> bf16 hi/lo ----
    #pragma unroll
    for (int it = 0; it < 16; ++it) {
        int s = it * 256 + t;       // 0..4095 float4 slots
        int r = s >> 6;             // row 0..63
        int ks = (s & 63) * 4;      // k 0..252
        int grow = rowBase + r;
        float4 v = make_float4(0.f, 0.f, 0.f, 0.f);
        if (grow < NNODES) v = *(const float4*)(x + (size_t)grow * IN_DIM + ks);
        unsigned short h0 = f2bf_rne(v.x), h1 = f2bf_rne(v.y),
                       h2 = f2bf_rne(v.z), h3 = f2bf_rne(v.w);
        unsigned short l0 = f2bf_rne(v.x - bf2f(h0)), l1 = f2bf_rne(v.y - bf2f(h1)),
                       l2 = f2bf_rne(v.z - bf2f(h2)), l3 = f2bf_rne(v.w - bf2f(h3));
        uint2 ph, pl;
        ph.x = (unsigned int)h0 | ((unsigned int)h1 << 16);
        ph.y = (unsigned int)h2 | ((unsigned int)h3 << 16);
        pl.x = (unsigned int)l0 | ((unsigned int)l1 << 16);
        pl.y = (unsigned int)l2 | ((unsigned int)l3 << 16);
        *(uint2*)&xhi[r][ks] = ph;
        *(uint2*)&xlo[r][ks] = pl;
    }
    __syncthreads();

    // ---- MFMA main loop: only LDS reads + MFMAs ----
    f32x4 acc[4][2];
    #pragma unroll
    for (int m = 0; m < 4; ++m)
        #pragma unroll
        for (int j = 0; j < 2; ++j) {
            acc[m][j][0] = bias[j]; acc[m][j][1] = bias[j];
            acc[m][j][2] = bias[j]; acc[m][j][3] = bias[j];
        }

    #pragma unroll
    for (int kt = 0; kt < 8; ++kt) {
        const int kb = kt * 32 + q * 8;
        #pragma unroll
        for (int m = 0; m < 4; ++m) {
            bf16x8 ah = *(const bf16x8*)&xhi[m * 16 + c][kb];
            bf16x8 al = *(const bf16x8*)&xlo[m * 16 + c][kb];
            #pragma unroll
            for (int j = 0; j < 2; ++j) {
                acc[m][j] = __builtin_amdgcn_mfma_f32_16x16x32_bf16(ah, wh[j][kt], acc[m][j], 0, 0, 0);
                acc[m][j] = __builtin_amdgcn_mfma_f32_16x16x32_bf16(al, wh[j][kt], acc[m][j], 0, 0, 0);
                acc[m][j] = __builtin_amdgcn_mfma_f32_16x16x32_bf16(ah, wl[j][kt], acc[m][j], 0, 0, 0);
            }
        }
    }

    // ---- row L2-norm: butterfly over 16 c-lanes, then cross-wave LDS reduce ----
    float psum[4][4];  // [m][r]: partial sum over this wave's 32 cols
    #pragma unroll
    for (int m = 0; m < 4; ++m)
        #pragma unroll
        for (int r = 0; r < 4; ++r) {
            float s = acc[m][0][r] * acc[m][0][r] + acc[m][1][r] * acc[m][1][r];
            psum[m][r] = s;
        }
    #pragma unroll
    for (int mask = 1; mask < 16; mask <<= 1)
        #pragma unroll
        for (int m = 0; m < 4; ++m)
            #pragma unroll
            for (int r = 0; r < 4; ++r)
                psum[m][r] += __shfl_xor(psum[m][r], mask);

    __syncthreads();  // done reading xhi/xlo; reuse as reduction scratch
    float* red = (float*)&xhi[0][0];      // red[row*8 + wv], 64*8 floats
    float* scl = red + 64 * 8;            // scl[row], 64 floats
    if (c == 0) {
        #pragma unroll
        for (int m = 0; m < 4; ++m)
            #pragma unroll
            for (int r = 0; r < 4; ++r)
                red[(m * 16 + q * 4 + r) * 8 + wv] = psum[m][r];
    }
    __syncthreads();
    if (t < 64) {
        float s = red[t * 8 + 0] + red[t * 8 + 1] + red[t * 8 + 2] + red[t * 8 + 3];
        scl[t] = SCALE / fmaxf(sqrtf(s), 1e-12f);
    }
    __syncthreads();

    // ---- store hn (fp32) + zb (bf16) ----
    #pragma unroll
    for (int m = 0; m < 4; ++m) {
        #pragma unroll
        for (int r = 0; r < 4; ++r) {
            int lrow = m * 16 + q * 4 + r;
            int grow = rowBase + lrow;
            if (grow < NNODES) {
                float sc = scl[lrow];
                #pragma unroll
                for (int j = 0; j < 2; ++j) {
                    float o = acc[m][j][r] * sc;
                    size_t idx = (size_t)grow * OUT_DIM + (2 * wv + j) * 16 + c;
                    hn[idx] = o;
                    zb[idx] = f2bf_rne(o);
                }
            }
        }
    }
}

// ---------------- gather propagation: wave-per-node, bf16 state ----------------

template <int FINAL>
__global__ void __launch_bounds__(256) gather_kernel(
        const int* __restrict__ off, const int* __restrict__ csr_row,
        const float* __restrict__ csr_w, const float* __restrict__ selfw,
        const unsigned int* __restrict__ zb, const float* __restrict__ hn,
        unsigned int* __restrict__ zout_b, float* __restrict__ zout_f) {
    const int wv = threadIdx.x >> 6;
    const int lane = threadIdx.x & 63;
    const int c = blockIdx.x * 4 + wv;  // grid*4 == NNODES exactly
    const int s = off[c];
    const int e = off[c + 1];

    float2 acc;
    {
        float sw = selfw[c];
        float2 zc = bf2_to_f2(zb[(size_t)c * 64 + lane]);
        acc.x = sw * zc.x;
        acc.y = sw * zc.y;
    }

    for (int base = s; base < e; base += 64) {
        int n = e - base;
        if (n > 64) n = 64;
        int idx = 0;
        float w = 0.f;
        if (lane < n) {
            idx = csr_row[base + lane];
            w = csr_w[base + lane];
        }
        int j = 0;
        for (; j + 4 <= n; j += 4) {
            int r0 = __shfl(idx, j + 0), r1 = __shfl(idx, j + 1);
            int r2 = __shfl(idx, j + 2), r3 = __shfl(idx, j + 3);
            float w0 = __shfl(w, j + 0), w1 = __shfl(w, j + 1);
            float w2 = __shfl(w, j + 2), w3 = __shfl(w, j + 3);
            unsigned int p0 = zb[(size_t)r0 * 64 + lane];
            unsigned int p1 = zb[(size_t)r1 * 64 + lane];
            unsigned int p2 = zb[(size_t)r2 * 64 + lane];
            unsigned int p3 = zb[(size_t)r3 * 64 + lane];
            float2 v0 = bf2_to_f2(p0), v1 = bf2_to_f2(p1);
            float2 v2 = bf2_to_f2(p2), v3 = bf2_to_f2(p3);
            acc.x += w0 * v0.x; acc.y += w0 * v0.y;
            acc.x += w1 * v1.x; acc.y += w1 * v1.y;
            acc.x += w2 * v2.x; acc.y += w2 * v2.y;
            acc.x += w3 * v3.x; acc.y += w3 * v3.y;
        }
        for (; j < n; ++j) {
            int r = __shfl(idx, j);
            float ww = __shfl(w, j);
            float2 v = bf2_to_f2(zb[(size_t)r * 64 + lane]);
            acc.x += ww * v.x;
            acc.y += ww * v.y;
        }
    }

    float2 h = ((const float2*)hn)[(size_t)c * 64 + lane];
    float ox = acc.x + ALPHA * h.x;
    float oy = acc.y + ALPHA * h.y;
    if (FINAL) {
        ((float2*)zout_f)[(size_t)c * 64 + lane] = make_float2(ox, oy);
    } else {
        zout_b[(size_t)c * 64 + lane] = f2_to_bf2(ox, oy);
    }
}

extern "C" void kernel_launch(void* const* d_in, const int* in_sizes, int n_in,
                              void* d_out, int out_size, void* d_ws, size_t ws_size,
                              hipStream_t stream) {
    const float* x  = (const float*)d_in[0];
    const int*   ei = (const int*)d_in[1];
    const float* W  = (const float*)d_in[2];
    const float* b  = (const float*)d_in[3];
    float* out = (float*)d_out;

    int E = in_sizes[1] / 2;
    const int* row = ei;       // sources
    const int* col = ei + E;   // targets

    // workspace layout
    float* dinv  = (float*)d_ws;                        // 50048
    float* selfw = dinv + 50048;                        // 50048
    float* hn    = selfw + 50048;                       // 6,400,000 fp32
    unsigned int* zb  = (unsigned int*)(hn + (size_t)NNODES * OUT_DIM);  // 3.2M u32 (bf16x2)
    unsigned int* z1b = zb + (size_t)NNODES * 64;                        // 3.2M u32
    int*   cnt   = (int*)(z1b + (size_t)NNODES * 64);   // 50048
    int*   off   = cnt + 50048;                         // 50112 (N+1 used)
    int*   cur   = off + 50112;                         // 50048
    int*   part  = cur + 50048;                         // 256
    int*   csr_row = part + 256;                        // E
    float* csr_w   = (float*)(csr_row + ((E + 63) & ~63));  // E
    ushort_t* Whi = (ushort_t*)(csr_w + ((E + 63) & ~63));  // 32768
    ushort_t* Wlo = Whi + OUT_DIM * IN_DIM;                 // 32768

    zero_cnt_kernel<<<(NNODES + 255) / 256, 256, 0, stream>>>(cnt);
    deg_scatter_kernel<<<(E + 255) / 256, 256, 0, stream>>>(col, cnt, E);
    wcvt_kernel<<<(OUT_DIM * IN_DIM + 255) / 256, 256, 0, stream>>>(W, Whi, Wlo);

    scan_pass1<<<NB_SCAN, 256, 0, stream>>>(cnt, part);
    scan_pass2<<<1, 256, 0, stream>>>(part);
    scan_pass3<<<NB_SCAN, 256, 0, stream>>>(cnt, part, off, cur, dinv, selfw, E);
    csr_fill_kernel<<<(E + 255) / 256, 256, 0, stream>>>(row, col, dinv, cur, csr_row, csr_w, E);

    gemm_norm_kernel<<<(NNODES + 63) / 64, 256, 0, stream>>>(x, Whi, Wlo, b, hn, (ushort_t*)zb);

    gather_kernel<0><<<NNODES / 4, 256, 0, stream>>>(off, csr_row, csr_w, selfw, zb, hn, z1b, nullptr);
    gather_kernel<1><<<NNODES / 4, 256, 0, stream>>>(off, csr_row, csr_w, selfw, z1b, hn, nullptr, out);
}

// Round 8
// 245.173 us; speedup vs baseline: 1.2455x; 1.0716x over previous
//
#include <hip/hip_runtime.h>
#include <hip/hip_bf16.h>

#define NNODES 50000
#define IN_DIM 256
#define OUT_DIM 128
#define SCALE 1.8f
#define ALPHA 0.15f
#define NB_SCAN 196  // ceil(50000/256)

typedef unsigned short ushort_t;
typedef __attribute__((ext_vector_type(8))) _Float16 f16x8;
typedef __attribute__((ext_vector_type(4))) float f32x4;

// ---------------- helpers ----------------

__device__ __forceinline__ unsigned short f2bf_rne(float f) {
    unsigned int u = __float_as_uint(f);
    unsigned int r = u + 0x7fffu + ((u >> 16) & 1u);  // round-to-nearest-even
    return (unsigned short)(r >> 16);
}

__device__ __forceinline__ float2 bf2_to_f2(unsigned int p) {
    float2 f;
    f.x = __uint_as_float(p << 16);
    f.y = __uint_as_float(p & 0xffff0000u);
    return f;
}

__device__ __forceinline__ unsigned int f2_to_bf2(float x, float y) {
    return (unsigned int)f2bf_rne(x) | ((unsigned int)f2bf_rne(y) << 16);
}

__device__ __forceinline__ unsigned short f2h(float f) {
    _Float16 h = (_Float16)f;  // RNE
    return *(unsigned short*)&h;
}

// ---------------- degree count ----------------

__global__ void deg_scatter_kernel(const int* __restrict__ col, int* __restrict__ cnt, int E) {
    int e = blockIdx.x * blockDim.x + threadIdx.x;
    if (e < E) atomicAdd(&cnt[col[e]], 1);
}

// ---------------- W -> fp16 ----------------

__global__ void wcvt_kernel(const float* __restrict__ W, ushort_t* __restrict__ Whf) {
    int i = blockIdx.x * blockDim.x + threadIdx.x;
    if (i < OUT_DIM * IN_DIM) Whf[i] = f2h(W[i]);
}

// ---------------- exclusive scan (3-pass) over cnt -> off, cur; fused dinv/selfw ----------------

__global__ void scan_pass1(const int* __restrict__ cnt, int* __restrict__ part) {
    __shared__ int sd[256];
    int t = threadIdx.x;
    int i = blockIdx.x * 256 + t;
    sd[t] = (i < NNODES) ? cnt[i] : 0;
    __syncthreads();
    for (int s = 128; s > 0; s >>= 1) {
        if (t < s) sd[t] += sd[t + s];
        __syncthreads();
    }
    if (t == 0) part[blockIdx.x] = sd[0];
}

__global__ void scan_pass2(int* __restrict__ part) {
    __shared__ int s[256];
    int t = threadIdx.x;
    int v = (t < NB_SCAN) ? part[t] : 0;
    s[t] = v;
    __syncthreads();
    for (int o = 1; o < 256; o <<= 1) {
        int u = (t >= o) ? s[t - o] : 0;
        __syncthreads();
        s[t] += u;
        __syncthreads();
    }
    if (t < NB_SCAN) part[t] = (t == 0) ? 0 : s[t - 1];
}

__global__ void scan_pass3(const int* __restrict__ cnt, const int* __restrict__ part,
                           int* __restrict__ off, int* __restrict__ cur,
                           float* __restrict__ dinv, float* __restrict__ selfw, int E) {
    __shared__ int s[256];
    int t = threadIdx.x;
    int i = blockIdx.x * 256 + t;
    int v = (i < NNODES) ? cnt[i] : 0;
    s[t] = v;
    __syncthreads();
    for (int o = 1; o < 256; o <<= 1) {
        int u = (t >= o) ? s[t - o] : 0;
        __syncthreads();
        s[t] += u;
        __syncthreads();
    }
    int excl = part[blockIdx.x] + ((t == 0) ? 0 : s[t - 1]);
    if (i < NNODES) {
        off[i] = excl;
        cur[i] = excl;
        float d = rsqrtf((float)(v + 1));
        dinv[i] = d;
        selfw[i] = (1.0f - ALPHA) * d * d;
    }
    if (i == NNODES - 1) off[NNODES] = E;
}

__global__ void csr_fill_kernel(const int* __restrict__ row, const int* __restrict__ col,
                                const float* __restrict__ dinv, int* __restrict__ cur,
                                int* __restrict__ csr_row, float* __restrict__ csr_w, int E) {
    int e = blockIdx.x * blockDim.x + threadIdx.x;
    if (e < E) {
        int c = col[e];
        int r = row[e];
        int p = atomicAdd(&cur[c], 1);
        csr_row[p] = r;
        csr_w[p] = (1.0f - ALPHA) * dinv[r] * dinv[c];
    }
}

// ---------------- MFMA GEMM + bias + L2-normalize (pure fp16 inputs) ----------------
// Block = 256 thr = 4 waves, tile 64 rows x 128 cols. Wave wv computes ALL 64 rows x
// 32 cols: 4 m-tiles x 2 n-tiles. fp16 (11-bit mantissa) is accurate enough:
// products exact in fp32 accumulator; output error ~3.5e-4 << 3.28e-3 threshold.
// W working set = 2n x 8kt = 16 frags = 64 VGPRs -- exactly the footprint R7's
// compiler hoisted (it refused at 128). No global loads in the MFMA loop.
// C/D layout: col = lane&15, row = (lane>>4)*4 + reg  [m89-verified].
// A layout:  A[m = lane&15][k = (lane>>4)*8 + j]      [m120-verified].

#define XPAD 264  // 256 + 8 halfs; row stride 528 B (16B-aligned)

__global__ void __launch_bounds__(256, 4) gemm_norm_kernel(
        const float* __restrict__ x, const ushort_t* __restrict__ Whf,
        const float* __restrict__ b, ushort_t* __restrict__ zb) {
    __shared__ __align__(16) ushort_t xh[64][XPAD];

    const int t = threadIdx.x;
    const int wv = t >> 6;
    const int lane = t & 63;
    const int q = lane >> 4;     // quad 0..3
    const int c = lane & 15;
    const int rowBase = blockIdx.x * 64;

    // ---- W fragment preload (loop-invariant, 64 VGPRs; latency buried under staging) ----
    f16x8 wf[2][8];
    float bias[2];
    #pragma unroll
    for (int j = 0; j < 2; ++j) {
        const size_t base = (size_t)((2 * wv + j) * 16 + c) * IN_DIM + q * 8;
        #pragma unroll
        for (int kt = 0; kt < 8; ++kt)
            wf[j][kt] = *(const f16x8*)(Whf + base + kt * 32);
        bias[j] = b[(2 * wv + j) * 16 + c];
    }

    // ---- stage x (64 rows x 256 k), fp32 -> fp16 ----
    #pragma unroll
    for (int it = 0; it < 16; ++it) {
        int s = it * 256 + t;       // float4 slot
        int r = s >> 6;             // row 0..63
        int ks = (s & 63) * 4;      // k 0..252
        int grow = rowBase + r;
        float4 v = make_float4(0.f, 0.f, 0.f, 0.f);
        if (grow < NNODES) v = *(const float4*)(x + (size_t)grow * IN_DIM + ks);
        uint2 p;
        p.x = (unsigned int)f2h(v.x) | ((unsigned int)f2h(v.y) << 16);
        p.y = (unsigned int)f2h(v.z) | ((unsigned int)f2h(v.w) << 16);
        *(uint2*)&xh[r][ks] = p;
    }
    __syncthreads();

    // ---- MFMA main loop: only LDS reads + MFMAs ----
    f32x4 acc[4][2];
    #pragma unroll
    for (int m = 0; m < 4; ++m)
        #pragma unroll
        for (int j = 0; j < 2; ++j) {
            acc[m][j][0] = bias[j]; acc[m][j][1] = bias[j];
            acc[m][j][2] = bias[j]; acc[m][j][3] = bias[j];
        }

    #pragma unroll
    for (int kt = 0; kt < 8; ++kt) {
        const int kb = kt * 32 + q * 8;
        #pragma unroll
        for (int m = 0; m < 4; ++m) {
            f16x8 a = *(const f16x8*)&xh[m * 16 + c][kb];
            #pragma unroll
            for (int j = 0; j < 2; ++j)
                acc[m][j] = __builtin_amdgcn_mfma_f32_16x16x32_f16(a, wf[j][kt], acc[m][j], 0, 0, 0);
        }
    }

    // ---- row L2-norm: butterfly over 16 c-lanes, then cross-wave LDS reduce ----
    float psum[4][4];
    #pragma unroll
    for (int m = 0; m < 4; ++m)
        #pragma unroll
        for (int r = 0; r < 4; ++r)
            psum[m][r] = acc[m][0][r] * acc[m][0][r] + acc[m][1][r] * acc[m][1][r];
    #pragma unroll
    for (int mask = 1; mask < 16; mask <<= 1)
        #pragma unroll
        for (int m = 0; m < 4; ++m)
            #pragma unroll
            for (int r = 0; r < 4; ++r)
                psum[m][r] += __shfl_xor(psum[m][r], mask);

    __syncthreads();  // done reading xh; reuse as reduction scratch
    float* red = (float*)&xh[0][0];       // red[row*8 + wv], 64*8 floats
    float* scl = red + 64 * 8;            // scl[row], 64 floats
    if (c == 0) {
        #pragma unroll
        for (int m = 0; m < 4; ++m)
            #pragma unroll
            for (int r = 0; r < 4; ++r)
                red[(m * 16 + q * 4 + r) * 8 + wv] = psum[m][r];
    }
    __syncthreads();
    if (t < 64) {
        float s = red[t * 8 + 0] + red[t * 8 + 1] + red[t * 8 + 2] + red[t * 8 + 3];
        scl[t] = SCALE / fmaxf(sqrtf(s), 1e-12f);
    }
    __syncthreads();

    // ---- store zb (bf16) ----
    #pragma unroll
    for (int m = 0; m < 4; ++m) {
        #pragma unroll
        for (int r = 0; r < 4; ++r) {
            int lrow = m * 16 + q * 4 + r;
            int grow = rowBase + lrow;
            if (grow < NNODES) {
                float sc = scl[lrow];
                #pragma unroll
                for (int j = 0; j < 2; ++j) {
                    float o = acc[m][j][r] * sc;
                    zb[(size_t)grow * OUT_DIM + (2 * wv + j) * 16 + c] = f2bf_rne(o);
                }
            }
        }
    }
}

// ---------------- gather propagation: wave-per-node, bf16 state ----------------
// Round 1 (FINAL=0): z = h, so alpha*h folds into the self coefficient:
//   out = sum csr_w*z + (selfw + ALPHA)*z_c           -> write bf16
// Round 2 (FINAL=1): out = sum csr_w*z + selfw*z_c + ALPHA*h(zb bf16) -> write fp32

template <int FINAL>
__global__ void __launch_bounds__(256) gather_kernel(
        const int* __restrict__ off, const int* __restrict__ csr_row,
        const float* __restrict__ csr_w, const float* __restrict__ selfw,
        const unsigned int* __restrict__ zst, const unsigned int* __restrict__ hb,
        unsigned int* __restrict__ zout_b, float* __restrict__ zout_f) {
    const int wv = threadIdx.x >> 6;
    const int lane = threadIdx.x & 63;
    const int c = blockIdx.x * 4 + wv;  // grid*4 == NNODES exactly
    const int s = off[c];
    const int e = off[c + 1];

    float2 acc;
    {
        float sw = selfw[c] + (FINAL ? 0.0f : ALPHA);
        float2 zc = bf2_to_f2(zst[(size_t)c * 64 + lane]);
        acc.x = sw * zc.x;
        acc.y = sw * zc.y;
    }

    for (int base = s; base < e; base += 64) {
        int n = e - base;
        if (n > 64) n = 64;
        int idx = 0;
        float w = 0.f;
        if (lane < n) {
            idx = csr_row[base + lane];
            w = csr_w[base + lane];
        }
        int j = 0;
        for (; j + 4 <= n; j += 4) {
            int r0 = __shfl(idx, j + 0), r1 = __shfl(idx, j + 1);
            int r2 = __shfl(idx, j + 2), r3 = __shfl(idx, j + 3);
            float w0 = __shfl(w, j + 0), w1 = __shfl(w, j + 1);
            float w2 = __shfl(w, j + 2), w3 = __shfl(w, j + 3);
            unsigned int p0 = zst[(size_t)r0 * 64 + lane];
            unsigned int p1 = zst[(size_t)r1 * 64 + lane];
            unsigned int p2 = zst[(size_t)r2 * 64 + lane];
            unsigned int p3 = zst[(size_t)r3 * 64 + lane];
            float2 v0 = bf2_to_f2(p0), v1 = bf2_to_f2(p1);
            float2 v2 = bf2_to_f2(p2), v3 = bf2_to_f2(p3);
            acc.x += w0 * v0.x; acc.y += w0 * v0.y;
            acc.x += w1 * v1.x; acc.y += w1 * v1.y;
            acc.x += w2 * v2.x; acc.y += w2 * v2.y;
            acc.x += w3 * v3.x; acc.y += w3 * v3.y;
        }
        for (; j < n; ++j) {
            int r = __shfl(idx, j);
            float ww = __shfl(w, j);
            float2 v = bf2_to_f2(zst[(size_t)r * 64 + lane]);
            acc.x += ww * v.x;
            acc.y += ww * v.y;
        }
    }

    if (FINAL) {
        float2 h = bf2_to_f2(hb[(size_t)c * 64 + lane]);
        float ox = acc.x + ALPHA * h.x;
        float oy = acc.y + ALPHA * h.y;
        ((float2*)zout_f)[(size_t)c * 64 + lane] = make_float2(ox, oy);
    } else {
        zout_b[(size_t)c * 64 + lane] = f2_to_bf2(acc.x, acc.y);
    }
}

extern "C" void kernel_launch(void* const* d_in, const int* in_sizes, int n_in,
                              void* d_out, int out_size, void* d_ws, size_t ws_size,
                              hipStream_t stream) {
    const float* x  = (const float*)d_in[0];
    const int*   ei = (const int*)d_in[1];
    const float* W  = (const float*)d_in[2];
    const float* b  = (const float*)d_in[3];
    float* out = (float*)d_out;

    int E = in_sizes[1] / 2;
    const int* row = ei;       // sources
    const int* col = ei + E;   // targets

    // workspace layout
    float* dinv  = (float*)d_ws;                        // 50048
    float* selfw = dinv + 50048;                        // 50048
    unsigned int* zb  = (unsigned int*)(selfw + 50048); // 3.2M u32 (bf16x2) = h
    unsigned int* z1b = zb + (size_t)NNODES * 64;       // 3.2M u32
    int*   cnt   = (int*)(z1b + (size_t)NNODES * 64);   // 50048
    int*   off   = cnt + 50048;                         // 50112 (N+1 used)
    int*   cur   = off + 50112;                         // 50048
    int*   part  = cur + 50048;                         // 256
    int*   csr_row = part + 256;                        // E
    float* csr_w   = (float*)(csr_row + ((E + 63) & ~63));  // E
    ushort_t* Whf  = (ushort_t*)(csr_w + ((E + 63) & ~63)); // 32768

    hipMemsetAsync(cnt, 0, NNODES * sizeof(int), stream);
    deg_scatter_kernel<<<(E + 255) / 256, 256, 0, stream>>>(col, cnt, E);
    wcvt_kernel<<<(OUT_DIM * IN_DIM + 255) / 256, 256, 0, stream>>>(W, Whf);

    scan_pass1<<<NB_SCAN, 256, 0, stream>>>(cnt, part);
    scan_pass2<<<1, 256, 0, stream>>>(part);
    scan_pass3<<<NB_SCAN, 256, 0, stream>>>(cnt, part, off, cur, dinv, selfw, E);
    csr_fill_kernel<<<(E + 255) / 256, 256, 0, stream>>>(row, col, dinv, cur, csr_row, csr_w, E);

    gemm_norm_kernel<<<(NNODES + 63) / 64, 256, 0, stream>>>(x, Whf, b, (ushort_t*)zb);

    gather_kernel<0><<<NNODES / 4, 256, 0, stream>>>(off, csr_row, csr_w, selfw, zb, nullptr, z1b, nullptr);
    gather_kernel<1><<<NNODES / 4, 256, 0, stream>>>(off, csr_row, csr_w, selfw, z1b, zb, nullptr, out);
}

// Round 9
// 234.194 us; speedup vs baseline: 1.3039x; 1.0469x over previous
//
#include <hip/hip_runtime.h>
#include <hip/hip_bf16.h>

#define NNODES 50000
#define IN_DIM 256
#define OUT_DIM 128
#define SCALE 1.8f
#define ALPHA 0.15f
#define NB_SCAN 196  // ceil(50000/256)

typedef unsigned short ushort_t;
typedef __attribute__((ext_vector_type(8))) _Float16 f16x8;
typedef __attribute__((ext_vector_type(4))) float f32x4;

// ---------------- helpers ----------------

__device__ __forceinline__ unsigned short f2bf_rne(float f) {
    unsigned int u = __float_as_uint(f);
    unsigned int r = u + 0x7fffu + ((u >> 16) & 1u);  // round-to-nearest-even
    return (unsigned short)(r >> 16);
}

__device__ __forceinline__ float2 bf2_to_f2(unsigned int p) {
    float2 f;
    f.x = __uint_as_float(p << 16);
    f.y = __uint_as_float(p & 0xffff0000u);
    return f;
}

__device__ __forceinline__ unsigned int f2_to_bf2(float x, float y) {
    return (unsigned int)f2bf_rne(x) | ((unsigned int)f2bf_rne(y) << 16);
}

__device__ __forceinline__ unsigned short f2h(float f) {
    _Float16 h = (_Float16)f;  // RNE
    return *(unsigned short*)&h;
}

// ---------------- degree count ----------------

__global__ void deg_scatter_kernel(const int* __restrict__ col, int* __restrict__ cnt, int E) {
    int e = blockIdx.x * blockDim.x + threadIdx.x;
    if (e < E) atomicAdd(&cnt[col[e]], 1);
}

// ---------------- W -> fp16 ----------------

__global__ void wcvt_kernel(const float* __restrict__ W, ushort_t* __restrict__ Whf) {
    int i = blockIdx.x * blockDim.x + threadIdx.x;
    if (i < OUT_DIM * IN_DIM) Whf[i] = f2h(W[i]);
}

// ---------------- exclusive scan (3-pass) over cnt; fused per-node coefficients ----------------
// dinv = rsqrt(deg+1); q = (1-a)*dinv^2 (round-1 state coeff);
// gr = ((1-a)*dinv, a/dinv) (round-2 output coeffs).

__global__ void scan_pass1(const int* __restrict__ cnt, int* __restrict__ part) {
    __shared__ int sd[256];
    int t = threadIdx.x;
    int i = blockIdx.x * 256 + t;
    sd[t] = (i < NNODES) ? cnt[i] : 0;
    __syncthreads();
    for (int s = 128; s > 0; s >>= 1) {
        if (t < s) sd[t] += sd[t + s];
        __syncthreads();
    }
    if (t == 0) part[blockIdx.x] = sd[0];
}

__global__ void scan_pass2(int* __restrict__ part) {
    __shared__ int s[256];
    int t = threadIdx.x;
    int v = (t < NB_SCAN) ? part[t] : 0;
    s[t] = v;
    __syncthreads();
    for (int o = 1; o < 256; o <<= 1) {
        int u = (t >= o) ? s[t - o] : 0;
        __syncthreads();
        s[t] += u;
        __syncthreads();
    }
    if (t < NB_SCAN) part[t] = (t == 0) ? 0 : s[t - 1];
}

__global__ void scan_pass3(const int* __restrict__ cnt, const int* __restrict__ part,
                           int* __restrict__ off, int* __restrict__ cur,
                           float* __restrict__ dinv, float* __restrict__ q,
                           float2* __restrict__ gr, int E) {
    __shared__ int s[256];
    int t = threadIdx.x;
    int i = blockIdx.x * 256 + t;
    int v = (i < NNODES) ? cnt[i] : 0;
    s[t] = v;
    __syncthreads();
    for (int o = 1; o < 256; o <<= 1) {
        int u = (t >= o) ? s[t - o] : 0;
        __syncthreads();
        s[t] += u;
        __syncthreads();
    }
    int excl = part[blockIdx.x] + ((t == 0) ? 0 : s[t - 1]);
    if (i < NNODES) {
        off[i] = excl;
        cur[i] = excl;
        float deg = (float)(v + 1);
        float d = rsqrtf(deg);
        dinv[i] = d;
        q[i] = (1.0f - ALPHA) * d * d;
        gr[i] = make_float2((1.0f - ALPHA) * d, ALPHA * sqrtf(deg));  // a/dinv = a*sqrt(deg)
    }
    if (i == NNODES - 1) off[NNODES] = E;
}

// single scattered 4B store per edge (R8: csr_w eliminated algebraically)
__global__ void csr_fill_kernel(const int* __restrict__ row, const int* __restrict__ col,
                                int* __restrict__ cur, int* __restrict__ csr_row, int E) {
    int e = blockIdx.x * blockDim.x + threadIdx.x;
    if (e < E) {
        int c = col[e];
        int p = atomicAdd(&cur[c], 1);
        csr_row[p] = row[e];
    }
}

// ---------------- MFMA GEMM + bias + L2-normalize (pure fp16 inputs) ----------------
// Writes s0 = bf16(dinv * normalize(xW^T+b) * SCALE) -- the dinv-scaled propagation
// state (dinv folded into the per-row scale for free).
// C/D layout: col = lane&15, row = (lane>>4)*4 + reg  [m89-verified].
// A layout:  A[m = lane&15][k = (lane>>4)*8 + j]      [m120-verified].

#define XPAD 264  // 256 + 8 halfs; row stride 528 B (16B-aligned)

__global__ void __launch_bounds__(256, 4) gemm_norm_kernel(
        const float* __restrict__ x, const ushort_t* __restrict__ Whf,
        const float* __restrict__ b, const float* __restrict__ dinv,
        ushort_t* __restrict__ s0b) {
    __shared__ __align__(16) ushort_t xh[64][XPAD];

    const int t = threadIdx.x;
    const int wv = t >> 6;
    const int lane = t & 63;
    const int q = lane >> 4;     // quad 0..3
    const int c = lane & 15;
    const int rowBase = blockIdx.x * 64;

    // ---- W fragment preload (loop-invariant, 64 VGPRs; latency buried under staging) ----
    f16x8 wf[2][8];
    float bias[2];
    #pragma unroll
    for (int j = 0; j < 2; ++j) {
        const size_t base = (size_t)((2 * wv + j) * 16 + c) * IN_DIM + q * 8;
        #pragma unroll
        for (int kt = 0; kt < 8; ++kt)
            wf[j][kt] = *(const f16x8*)(Whf + base + kt * 32);
        bias[j] = b[(2 * wv + j) * 16 + c];
    }

    // ---- stage x (64 rows x 256 k), fp32 -> fp16 ----
    #pragma unroll
    for (int it = 0; it < 16; ++it) {
        int s = it * 256 + t;       // float4 slot
        int r = s >> 6;             // row 0..63
        int ks = (s & 63) * 4;      // k 0..252
        int grow = rowBase + r;
        float4 v = make_float4(0.f, 0.f, 0.f, 0.f);
        if (grow < NNODES) v = *(const float4*)(x + (size_t)grow * IN_DIM + ks);
        uint2 p;
        p.x = (unsigned int)f2h(v.x) | ((unsigned int)f2h(v.y) << 16);
        p.y = (unsigned int)f2h(v.z) | ((unsigned int)f2h(v.w) << 16);
        *(uint2*)&xh[r][ks] = p;
    }
    __syncthreads();

    // ---- MFMA main loop: only LDS reads + MFMAs ----
    f32x4 acc[4][2];
    #pragma unroll
    for (int m = 0; m < 4; ++m)
        #pragma unroll
        for (int j = 0; j < 2; ++j) {
            acc[m][j][0] = bias[j]; acc[m][j][1] = bias[j];
            acc[m][j][2] = bias[j]; acc[m][j][3] = bias[j];
        }

    #pragma unroll
    for (int kt = 0; kt < 8; ++kt) {
        const int kb = kt * 32 + q * 8;
        #pragma unroll
        for (int m = 0; m < 4; ++m) {
            f16x8 a = *(const f16x8*)&xh[m * 16 + c][kb];
            #pragma unroll
            for (int j = 0; j < 2; ++j)
                acc[m][j] = __builtin_amdgcn_mfma_f32_16x16x32_f16(a, wf[j][kt], acc[m][j], 0, 0, 0);
        }
    }

    // ---- row L2-norm: butterfly over 16 c-lanes, then cross-wave LDS reduce ----
    float psum[4][4];
    #pragma unroll
    for (int m = 0; m < 4; ++m)
        #pragma unroll
        for (int r = 0; r < 4; ++r)
            psum[m][r] = acc[m][0][r] * acc[m][0][r] + acc[m][1][r] * acc[m][1][r];
    #pragma unroll
    for (int mask = 1; mask < 16; mask <<= 1)
        #pragma unroll
        for (int m = 0; m < 4; ++m)
            #pragma unroll
            for (int r = 0; r < 4; ++r)
                psum[m][r] += __shfl_xor(psum[m][r], mask);

    __syncthreads();  // done reading xh; reuse as reduction scratch
    float* red = (float*)&xh[0][0];       // red[row*8 + wv], 64*8 floats
    float* scl = red + 64 * 8;            // scl[row], 64 floats
    if (c == 0) {
        #pragma unroll
        for (int m = 0; m < 4; ++m)
            #pragma unroll
            for (int r = 0; r < 4; ++r)
                red[(m * 16 + q * 4 + r) * 8 + wv] = psum[m][r];
    }
    __syncthreads();
    if (t < 64) {
        float s = red[t * 8 + 0] + red[t * 8 + 1] + red[t * 8 + 2] + red[t * 8 + 3];
        // fold dinv into the scale: state s0 = dinv * h  (OOB dinv read is harmless)
        scl[t] = dinv[rowBase + t] * SCALE / fmaxf(sqrtf(s), 1e-12f);
    }
    __syncthreads();

    // ---- store s0 (bf16 state) ----
    #pragma unroll
    for (int m = 0; m < 4; ++m) {
        #pragma unroll
        for (int r = 0; r < 4; ++r) {
            int lrow = m * 16 + q * 4 + r;
            int grow = rowBase + lrow;
            if (grow < NNODES) {
                float sc = scl[lrow];
                #pragma unroll
                for (int j = 0; j < 2; ++j) {
                    float o = acc[m][j][r] * sc;
                    s0b[(size_t)grow * OUT_DIM + (2 * wv + j) * 16 + c] = f2bf_rne(o);
                }
            }
        }
    }
}

// ---------------- gather propagation: wave-per-node, UNWEIGHTED sum of dinv-scaled state ----
// acctot = sum_in s[r] + s[c]
// Round 1 (FINAL=0, s == s0): s1[c] = q[c]*acctot + ALPHA*s0[c]        -> bf16
// Round 2 (FINAL=1):          out[c] = gr.x*acctot + gr.y*s0[c]        -> fp32

template <int FINAL>
__global__ void __launch_bounds__(256) gather_kernel(
        const int* __restrict__ off, const int* __restrict__ csr_row,
        const float* __restrict__ q, const float2* __restrict__ gr,
        const unsigned int* __restrict__ sin, const unsigned int* __restrict__ s0,
        unsigned int* __restrict__ sout_b, float* __restrict__ out_f) {
    const int wv = threadIdx.x >> 6;
    const int lane = threadIdx.x & 63;
    const int c = blockIdx.x * 4 + wv;  // grid*4 == NNODES exactly
    const int s = off[c];
    const int e = off[c + 1];

    float2 acc;
    float2 zc0;  // s0[c] (round1: sin==s0 so this is also the self term)
    {
        float2 zc = bf2_to_f2(sin[(size_t)c * 64 + lane]);
        acc = zc;  // self term of acctot
        zc0 = FINAL ? bf2_to_f2(s0[(size_t)c * 64 + lane]) : zc;
    }

    for (int base = s; base < e; base += 64) {
        int n = e - base;
        if (n > 64) n = 64;
        int idx = 0;
        if (lane < n) idx = csr_row[base + lane];
        int j = 0;
        for (; j + 4 <= n; j += 4) {
            int r0 = __shfl(idx, j + 0), r1 = __shfl(idx, j + 1);
            int r2 = __shfl(idx, j + 2), r3 = __shfl(idx, j + 3);
            unsigned int p0 = sin[(size_t)r0 * 64 + lane];
            unsigned int p1 = sin[(size_t)r1 * 64 + lane];
            unsigned int p2 = sin[(size_t)r2 * 64 + lane];
            unsigned int p3 = sin[(size_t)r3 * 64 + lane];
            float2 v0 = bf2_to_f2(p0), v1 = bf2_to_f2(p1);
            float2 v2 = bf2_to_f2(p2), v3 = bf2_to_f2(p3);
            acc.x += v0.x + v1.x + v2.x + v3.x;
            acc.y += v0.y + v1.y + v2.y + v3.y;
        }
        for (; j < n; ++j) {
            int r = __shfl(idx, j);
            float2 v = bf2_to_f2(sin[(size_t)r * 64 + lane]);
            acc.x += v.x;
            acc.y += v.y;
        }
    }

    if (FINAL) {
        float2 g = gr[c];
        float ox = g.x * acc.x + g.y * zc0.x;
        float oy = g.x * acc.y + g.y * zc0.y;
        ((float2*)out_f)[(size_t)c * 64 + lane] = make_float2(ox, oy);
    } else {
        float qc = q[c];
        float ox = qc * acc.x + ALPHA * zc0.x;
        float oy = qc * acc.y + ALPHA * zc0.y;
        sout_b[(size_t)c * 64 + lane] = f2_to_bf2(ox, oy);
    }
}

extern "C" void kernel_launch(void* const* d_in, const int* in_sizes, int n_in,
                              void* d_out, int out_size, void* d_ws, size_t ws_size,
                              hipStream_t stream) {
    const float* x  = (const float*)d_in[0];
    const int*   ei = (const int*)d_in[1];
    const float* W  = (const float*)d_in[2];
    const float* b  = (const float*)d_in[3];
    float* out = (float*)d_out;

    int E = in_sizes[1] / 2;
    const int* row = ei;       // sources
    const int* col = ei + E;   // targets

    // workspace layout
    float*  dinv = (float*)d_ws;                        // 50048
    float*  q    = dinv + 50048;                        // 50048
    float2* gr   = (float2*)(q + 50048);                // 50048 float2
    unsigned int* s0b = (unsigned int*)(gr + 50048);    // 3.2M u32 (bf16x2)
    unsigned int* s1b = s0b + (size_t)NNODES * 64;      // 3.2M u32
    int*   cnt   = (int*)(s1b + (size_t)NNODES * 64);   // 50048
    int*   off   = cnt + 50048;                         // 50112 (N+1 used)
    int*   cur   = off + 50112;                         // 50048
    int*   part  = cur + 50048;                         // 256
    int*   csr_row = part + 256;                        // E
    ushort_t* Whf  = (ushort_t*)(csr_row + ((E + 63) & ~63)); // 32768

    hipMemsetAsync(cnt, 0, NNODES * sizeof(int), stream);
    deg_scatter_kernel<<<(E + 255) / 256, 256, 0, stream>>>(col, cnt, E);
    wcvt_kernel<<<(OUT_DIM * IN_DIM + 255) / 256, 256, 0, stream>>>(W, Whf);

    scan_pass1<<<NB_SCAN, 256, 0, stream>>>(cnt, part);
    scan_pass2<<<1, 256, 0, stream>>>(part);
    scan_pass3<<<NB_SCAN, 256, 0, stream>>>(cnt, part, off, cur, dinv, q, gr, E);
    csr_fill_kernel<<<(E + 255) / 256, 256, 0, stream>>>(row, col, cur, csr_row, E);

    gemm_norm_kernel<<<(NNODES + 63) / 64, 256, 0, stream>>>(x, Whf, b, dinv, (ushort_t*)s0b);

    gather_kernel<0><<<NNODES / 4, 256, 0, stream>>>(off, csr_row, q, gr, s0b, s0b, s1b, nullptr);
    gather_kernel<1><<<NNODES / 4, 256, 0, stream>>>(off, csr_row, q, gr, s1b, s0b, nullptr, out);
}